// Round 1
// baseline (41.477 us; speedup 1.0000x reference)
//
#include <hip/hip_runtime.h>
#include <math.h>

#define NQ 4
#define NL 2

__device__ __forceinline__ float fast_tanh(float x) {
    // tanh(x) = 1 - 2/(exp(2x)+1); exact at +-inf saturation
    float e = __expf(x + x);                       // v_mul + v_exp_f32
    float r = __builtin_amdgcn_rcpf(e + 1.0f);     // v_add + v_rcp_f32
    return fmaf(-2.0f, r, 1.0f);                   // v_fma
}

extern "C" __global__ void __launch_bounds__(256)
hybrid_pinn_kernel(const float* __restrict__ x,
                   const float* __restrict__ ew1, const float* __restrict__ eb1,
                   const float* __restrict__ ew2, const float* __restrict__ eb2,
                   const float* __restrict__ pw,  const float* __restrict__ pb,
                   const float* __restrict__ qw,
                   const float* __restrict__ pw1, const float* __restrict__ pb1,
                   const float* __restrict__ pw2, const float* __restrict__ pb2,
                   float* __restrict__ out, int rows)
{
    const int row = blockIdx.x * blockDim.x + threadIdx.x;
    if (row >= rows) return;

    const float2 xv = reinterpret_cast<const float2*>(x)[row];

    // ---- encoder layer 1: 2 -> 64, tanh ----
    float z1[64];
#pragma unroll
    for (int j = 0; j < 64; ++j) {
        float a = fmaf(xv.y, ew1[64 + j], fmaf(xv.x, ew1[j], eb1[j]));
        z1[j] = fast_tanh(a);
    }

    // ---- encoder layer 2: 64 -> 16, tanh ----
    float z2[16];
#pragma unroll
    for (int j = 0; j < 16; ++j) z2[j] = eb2[j];
#pragma unroll
    for (int i = 0; i < 64; ++i) {
        float zi = z1[i];
#pragma unroll
        for (int j = 0; j < 16; ++j)
            z2[j] = fmaf(zi, ew2[i * 16 + j], z2[j]);
    }
#pragma unroll
    for (int j = 0; j < 16; ++j) z2[j] = fast_tanh(z2[j]);

    // ---- pre: 16 -> 4 ----
    float qin[NQ];
#pragma unroll
    for (int j = 0; j < NQ; ++j) qin[j] = pb[j];
#pragma unroll
    for (int i = 0; i < 16; ++i) {
        float zi = z2[i];
#pragma unroll
        for (int j = 0; j < NQ; ++j)
            qin[j] = fmaf(zi, pw[i * NQ + j], qin[j]);
    }

    // ---- quantum circuit: 16-dim real statevector ----
    // data-encoding RY on |0000> => product state
    // qubit q corresponds to bit (8 >> q) of the flat index
    float cq[NQ], sq[NQ];
#pragma unroll
    for (int q = 0; q < NQ; ++q)
        __sincosf(0.5f * qin[q], &sq[q], &cq[q]);

    float st[16];
#pragma unroll
    for (int i = 0; i < 16; ++i) {
        float v = ((i & 8) ? sq[0] : cq[0]);
        v *= ((i & 4) ? sq[1] : cq[1]);
        v *= ((i & 2) ? sq[2] : cq[2]);
        v *= ((i & 1) ? sq[3] : cq[3]);
        st[i] = v;
    }

#pragma unroll
    for (int l = 0; l < NL; ++l) {
        // uniform-angle RY on each qubit
#pragma unroll
        for (int q = 0; q < NQ; ++q) {
            float half = 0.5f * qw[l * NQ + q];
            float cc = __cosf(half);
            float ss = __sinf(half);
            const int bit = 8 >> q;
#pragma unroll
            for (int i = 0; i < 16; ++i) {
                if (i & bit) continue;
                float a0 = st[i], a1 = st[i | bit];
                st[i]       = fmaf(cc, a0, -ss * a1);
                st[i | bit] = fmaf(ss, a0,  cc * a1);
            }
        }
        // CNOT ring (0,1),(1,2),(2,3),(3,0): if ctrl bit set, swap target bit
        const int cn[4][2] = {{8, 4}, {4, 2}, {2, 1}, {1, 8}};
#pragma unroll
        for (int k = 0; k < 4; ++k) {
            const int bc = cn[k][0], bt = cn[k][1];
#pragma unroll
            for (int i = 0; i < 16; ++i) {
                if ((i & bc) && !(i & bt)) {
                    float t = st[i];
                    st[i] = st[i | bt];
                    st[i | bt] = t;
                }
            }
        }
    }

    // probabilities + Z expectations per qubit
    float p[16];
#pragma unroll
    for (int i = 0; i < 16; ++i) p[i] = st[i] * st[i];

    float qo[NQ];
#pragma unroll
    for (int q = 0; q < NQ; ++q) {
        const int bit = 8 >> q;
        float acc = 0.0f;
#pragma unroll
        for (int i = 0; i < 16; ++i)
            acc += (i & bit) ? -p[i] : p[i];
        qo[q] = acc;
    }

    // ---- post layer 1: 4 -> 32, tanh ----
    float h[32];
#pragma unroll
    for (int j = 0; j < 32; ++j) {
        float a = pb1[j];
#pragma unroll
        for (int i = 0; i < NQ; ++i)
            a = fmaf(qo[i], pw1[i * 32 + j], a);
        h[j] = fast_tanh(a);
    }

    // ---- post layer 2: 32 -> 4 ----
    float o[4];
#pragma unroll
    for (int j = 0; j < 4; ++j) o[j] = pb2[j];
#pragma unroll
    for (int i = 0; i < 32; ++i) {
        float hi = h[i];
#pragma unroll
        for (int j = 0; j < 4; ++j)
            o[j] = fmaf(hi, pw2[i * 4 + j], o[j]);
    }

    reinterpret_cast<float4*>(out)[row] = make_float4(o[0], o[1], o[2], o[3]);
}

extern "C" void kernel_launch(void* const* d_in, const int* in_sizes, int n_in,
                              void* d_out, int out_size, void* d_ws, size_t ws_size,
                              hipStream_t stream) {
    const float* x   = (const float*)d_in[0];
    const float* ew1 = (const float*)d_in[1];
    const float* eb1 = (const float*)d_in[2];
    const float* ew2 = (const float*)d_in[3];
    const float* eb2 = (const float*)d_in[4];
    const float* pw  = (const float*)d_in[5];
    const float* pb  = (const float*)d_in[6];
    const float* qw  = (const float*)d_in[7];
    const float* pw1 = (const float*)d_in[8];
    const float* pb1 = (const float*)d_in[9];
    const float* pw2 = (const float*)d_in[10];
    const float* pb2 = (const float*)d_in[11];
    float* out = (float*)d_out;

    const int rows = in_sizes[0] / 2;
    const int block = 256;
    const int grid = (rows + block - 1) / block;

    hipLaunchKernelGGL(hybrid_pinn_kernel, dim3(grid), dim3(block), 0, stream,
                       x, ew1, eb1, ew2, eb2, pw, pb, qw,
                       pw1, pb1, pw2, pb2, out, rows);
}